// Round 5
// baseline (734.740 us; speedup 1.0000x reference)
//
#include <hip/hip_runtime.h>
#include <math.h>

#define NB 512
#define NI 8192
#define NG (NI / 4)   // 2048 float4 item-groups per row
#define NLOG2 0.69314718055994530942f

__device__ __forceinline__ float log1mexp_f(float x) {
    // log(1 - exp(x)) for x <= 0, matching reference branch structure (precise ocml)
    return (x > -NLOG2) ? logf(-expm1f(x)) : log1pf(-expf(x));
}

__device__ int g_sel[NB];  // per-row selected index (decide -> writeout)

// ---------------- Kernel 1: prep + pack-transpose (verified in R3, unchanged) ----------
// float4 index (g*NB + b) holds items 4g..4g+3 of row b -> scan accesses fully coalesced.
#define TB 64   // rows per tile
#define TK 16   // float4-groups per tile (64 items)
__global__ __launch_bounds__(256) void prep_kernel(const float* __restrict__ logits,
                                                   float* __restrict__ Alp,   // ws: lp_p (later p_p)
                                                   float* __restrict__ Blq) { // out: lq_p
    __shared__ float4 lp_t[TB][TK + 1];
    __shared__ float4 lq_t[TB][TK + 1];
    int bx = blockIdx.x;
    int tb = (bx & 7) * TB;        // row-tile base (512/64 = 8 tiles)
    int tkb = (bx >> 3) * TK;      // group-tile base (2048/16 = 128 tiles)
    int t = threadIdx.x;

    int kl = t & 15;
    int rl0 = t >> 4;  // 0..15
#pragma unroll
    for (int r = 0; r < 4; ++r) {
        int row_local = r * 16 + rl0;
        float4 x4 = *(const float4*)&logits[(size_t)(tb + row_local) * NI + (size_t)(tkb + kl) * 4];
        float4 lp4, lq4;
        const float* xs = &x4.x;
        float* lps = &lp4.x;
        float* lqs = &lq4.x;
#pragma unroll
        for (int j = 0; j < 4; ++j) {
            float x = xs[j];
            float lp = -(fmaxf(-x, 0.0f) + log1pf(expf(-fabsf(x))));
            lp = fminf(lp, -1e-7f);
            lps[j] = lp;
            lqs[j] = log1mexp_f(lp);
        }
        lp_t[row_local][kl] = lp4;
        lq_t[row_local][kl] = lq4;
    }
    __syncthreads();

    int bl = t & 63;
    int kw0 = t >> 6;  // 0..3
#pragma unroll
    for (int w = 0; w < 4; ++w) {
        int k_local = w * 4 + kw0;
        size_t dst = (size_t)(tkb + k_local) * NB + (size_t)(tb + bl);
        ((float4*)Alp)[dst] = lp_t[bl][k_local];
        ((float4*)Blq)[dst] = lq_t[bl][k_local];
    }
}

// ---------------- Kernel 2: sequential per-row scan, 2 rows/lane, fused p ----------
// Bit-exact per-row op sequence (same as verified R0/R3 scan + decide's p computation):
//   x1 = S0+lp; x2 = S1+lq; d = x1-x2; m = max; S1 = fma(log2(1+exp2(-|d|*log2e)), ln2, m);
//   S0 += lq;  p = fminf(x1 - S1, 0)   [identical ops/order to R3 decide's fminf(x1-s1,0)]
// Two independent row-chains per lane hide the ~44-cy S1 dependency chain behind issue.
__device__ __forceinline__ void scan_step_p(float lp, float lq, float& S0, float& S1,
                                            float& po) {
    const float L2E = 1.44269504088896340736f;   // log2(e)
    const float LN2 = 0.69314718055994530942f;   // ln(2)
    float x1 = S0 + lp;
    float x2 = S1 + lq;
    float d  = x1 - x2;                          // never NaN (x1 finite)
    float m  = fmaxf(x1, x2);
    float z  = fabsf(d) * -L2E;
    float e  = __builtin_amdgcn_exp2f(z);        // exp2(-inf)=0 handles S1=-inf start
    float a  = 1.0f + e;
    float l  = __builtin_amdgcn_logf(a);
    S1 = fmaf(l, LN2, m);
    S0 = S0 + lq;
    po = fminf(x1 - S1, 0.0f);                   // decide's p, same op order as R3
}

#define SD 4  // float4-groups per chunk per row
__global__ __launch_bounds__(64, 1) void scan_kernel(float* __restrict__ A,
                                                     float* __restrict__ B) {
    int row = blockIdx.x * 64 + threadIdx.x;  // 4 blocks x 64 lanes -> rows [0,256)
    int row1 = row + 256;
    float4* Ap = (float4*)A;  // float4 index: g*NB + row
    float4* Bp = (float4*)B;

    float S0a = 0.0f, S1a = -INFINITY;
    float S0b = 0.0f, S1b = -INFINITY;

    float4 lpA0[SD], lqA0[SD], lpA1[SD], lqA1[SD];
    float4 lpB0[SD], lqB0[SD], lpB1[SD], lqB1[SD];

    // preload chunk 0 (both rows)
#pragma unroll
    for (int j = 0; j < SD; ++j) {
        lpA0[j] = Ap[(size_t)j * NB + row];
        lqA0[j] = Bp[(size_t)j * NB + row];
        lpA1[j] = Ap[(size_t)j * NB + row1];
        lqA1[j] = Bp[(size_t)j * NB + row1];
    }

    const int NCHUNK = NG / SD;  // 512 (even)
    for (int c = 0; c < NCHUNK; c += 2) {
        size_t g1 = (size_t)(c + 1) * SD;
        size_t g2 = (size_t)(c + 2) * SD;

        // prefetch chunk c+1 into B buffers
#pragma unroll
        for (int j = 0; j < SD; ++j) {
            lpB0[j] = Ap[(g1 + j) * NB + row];
            lqB0[j] = Bp[(g1 + j) * NB + row];
            lpB1[j] = Ap[(g1 + j) * NB + row1];
            lqB1[j] = Bp[(g1 + j) * NB + row1];
        }

        // compute + store chunk c (interleaved row0/row1 chains)
#pragma unroll
        for (int j = 0; j < SD; ++j) {
            float4 p0, p1;
            scan_step_p(lpA0[j].x, lqA0[j].x, S0a, S1a, p0.x);
            scan_step_p(lpA1[j].x, lqA1[j].x, S0b, S1b, p1.x);
            scan_step_p(lpA0[j].y, lqA0[j].y, S0a, S1a, p0.y);
            scan_step_p(lpA1[j].y, lqA1[j].y, S0b, S1b, p1.y);
            scan_step_p(lpA0[j].z, lqA0[j].z, S0a, S1a, p0.z);
            scan_step_p(lpA1[j].z, lqA1[j].z, S0b, S1b, p1.z);
            scan_step_p(lpA0[j].w, lqA0[j].w, S0a, S1a, p0.w);
            scan_step_p(lpA1[j].w, lqA1[j].w, S0b, S1b, p1.w);
            size_t g = (size_t)c * SD + j;
            Ap[g * NB + row] = p0;    // p overwrites lp_p (already consumed)
            Ap[g * NB + row1] = p1;
        }

        // prefetch chunk c+2 into A buffers
        if (c + 2 < NCHUNK) {
#pragma unroll
            for (int j = 0; j < SD; ++j) {
                lpA0[j] = Ap[(g2 + j) * NB + row];
                lqA0[j] = Bp[(g2 + j) * NB + row];
                lpA1[j] = Ap[(g2 + j) * NB + row1];
                lqA1[j] = Bp[(g2 + j) * NB + row1];
            }
        }

        // compute + store chunk c+1
#pragma unroll
        for (int j = 0; j < SD; ++j) {
            float4 p0, p1;
            scan_step_p(lpB0[j].x, lqB0[j].x, S0a, S1a, p0.x);
            scan_step_p(lpB1[j].x, lqB1[j].x, S0b, S1b, p1.x);
            scan_step_p(lpB0[j].y, lqB0[j].y, S0a, S1a, p0.y);
            scan_step_p(lpB1[j].y, lqB1[j].y, S0b, S1b, p1.y);
            scan_step_p(lpB0[j].z, lqB0[j].z, S0a, S1a, p0.z);
            scan_step_p(lpB1[j].z, lqB1[j].z, S0b, S1b, p1.z);
            scan_step_p(lpB0[j].w, lqB0[j].w, S0a, S1a, p0.w);
            scan_step_p(lpB1[j].w, lqB1[j].w, S0b, S1b, p1.w);
            Ap[(g1 + j) * NB + row] = p0;
            Ap[(g1 + j) * NB + row1] = p1;
        }
    }
}

// ---------------- Kernel 3: decide (reads packed p + row-major noise) -> g_sel ---------
// Same predicate math/op-order as verified R0/R3 decide: q = log1mexp(p); prob =
// sigmoid(p-q); select largest index with u < prob.
__global__ __launch_bounds__(256) void decide_kernel(const float* __restrict__ P,  // p_p
                                                     const float* __restrict__ noise) {
    int row = blockIdx.x;
    const float4* pp = (const float4*)P;
    const float4* ur = (const float4*)(noise + (size_t)row * NI);
    int tid = threadIdx.x;

    int best = -1;
#pragma unroll
    for (int k = 0; k < NG / 256; ++k) {  // 8
        int g = tid + k * 256;
        float4 p4 = pp[(size_t)g * NB + row];
        float4 u = ur[g];
#pragma unroll
        for (int j = 0; j < 4; ++j) {
            float p = (&p4.x)[j];
            float q = log1mexp_f(p);            // p==0 -> -inf -> prob 1
            float z = p - q;
            float prob = 1.0f / (1.0f + expf(-z));
            if ((&u.x)[j] < prob) {
                int i = 4 * g + j;
                best = (i > best) ? i : best;
            }
        }
    }

#pragma unroll
    for (int off = 32; off > 0; off >>= 1) {
        int o = __shfl_down(best, off);
        best = (o > best) ? o : best;
    }
    __shared__ int lds[4];
    int wid = tid >> 6;
    if ((tid & 63) == 0) lds[wid] = best;
    __syncthreads();
    if (tid == 0) {
        int s01 = (lds[0] > lds[1]) ? lds[0] : lds[1];
        int s23 = (lds[2] > lds[3]) ? lds[2] : lds[3];
        g_sel[row] = (s01 > s23) ? s01 : s23;
    }
}

// ---------------- Kernel 4: one-hot output write (row-major, verified in R3) -----------
__global__ __launch_bounds__(256) void writeout_kernel(float* __restrict__ out) {
    int row = blockIdx.x;
    int sel = g_sel[row];
    float4* outr = (float4*)(out + (size_t)row * NI);
    int tid = threadIdx.x;
#pragma unroll
    for (int k = 0; k < NG / 256; ++k) {
        int g = tid + k * 256;
        int i0 = 4 * g;
        float4 v;
        v.x = (i0 == sel) ? 1.0f : 0.0f;
        v.y = (i0 + 1 == sel) ? 1.0f : 0.0f;
        v.z = (i0 + 2 == sel) ? 1.0f : 0.0f;
        v.w = (i0 + 3 == sel) ? 1.0f : 0.0f;
        outr[g] = v;
    }
}

extern "C" void kernel_launch(void* const* d_in, const int* in_sizes, int n_in,
                              void* d_out, int out_size, void* d_ws, size_t ws_size,
                              hipStream_t stream) {
    (void)in_sizes; (void)n_in; (void)out_size; (void)ws_size;
    const float* logits = (const float*)d_in[0];
    const float* noise = (const float*)d_in[1];
    float* out = (float*)d_out;       // lq_p -> final 0/1 output (16 MB)
    float* A = (float*)d_ws;          // lp_p -> p_p (16 MB of ws)

    prep_kernel<<<8 * (NG / TK), 256, 0, stream>>>(logits, A, out);  // 1024 blocks
    scan_kernel<<<4, 64, 0, stream>>>(A, out);   // 256 lanes x 2 rows
    decide_kernel<<<NB, 256, 0, stream>>>(A, noise);
    writeout_kernel<<<NB, 256, 0, stream>>>(out);
}

// Round 8
// 420.565 us; speedup vs baseline: 1.7470x; 1.7470x over previous
//
#include <hip/hip_runtime.h>
#include <math.h>
#include <stdint.h>

#define NB 512
#define NI 8192
#define NG (NI / 4)   // 2048 float4 item-groups per row
#define NLOG2 0.69314718055994530942f

__device__ __forceinline__ float log1mexp_f(float x) {
    // log(1 - exp(x)) for x <= 0, matching reference branch structure (precise ocml)
    return (x > -NLOG2) ? logf(-expm1f(x)) : log1pf(-expf(x));
}

// Scan output p lives in its own module-allocated buffer: provably disjoint from the
// scan's load streams -> compiler needs no store->load drains (the R3 bottleneck).
__device__ float g_P[(size_t)NB * NI];

// ---------------- Kernel 1: prep + pack-transpose (verified R3/R5, unchanged) ----------
// float4 index (g*NB + b) holds items 4g..4g+3 of row b -> scan accesses fully coalesced.
#define TB 64   // rows per tile
#define TK 16   // float4-groups per tile (64 items)
__global__ __launch_bounds__(256) void prep_kernel(const float* __restrict__ logits,
                                                   float* __restrict__ Alp,   // ws: lp_p
                                                   float* __restrict__ Blq) { // out: lq_p
    __shared__ float4 lp_t[TB][TK + 1];
    __shared__ float4 lq_t[TB][TK + 1];
    int bx = blockIdx.x;
    int tb = (bx & 7) * TB;        // row-tile base (512/64 = 8 tiles)
    int tkb = (bx >> 3) * TK;      // group-tile base (2048/16 = 128 tiles)
    int t = threadIdx.x;

    int kl = t & 15;
    int rl0 = t >> 4;  // 0..15
#pragma unroll
    for (int r = 0; r < 4; ++r) {
        int row_local = r * 16 + rl0;
        float4 x4 = *(const float4*)&logits[(size_t)(tb + row_local) * NI + (size_t)(tkb + kl) * 4];
        float4 lp4, lq4;
        const float* xs = &x4.x;
        float* lps = &lp4.x;
        float* lqs = &lq4.x;
#pragma unroll
        for (int j = 0; j < 4; ++j) {
            float x = xs[j];
            float lp = -(fmaxf(-x, 0.0f) + log1pf(expf(-fabsf(x))));
            lp = fminf(lp, -1e-7f);
            lps[j] = lp;
            lqs[j] = log1mexp_f(lp);
        }
        lp_t[row_local][kl] = lp4;
        lq_t[row_local][kl] = lq4;
    }
    __syncthreads();

    int bl = t & 63;
    int kw0 = t >> 6;  // 0..3
#pragma unroll
    for (int w = 0; w < 4; ++w) {
        int k_local = w * 4 + kw0;
        size_t dst = (size_t)(tkb + k_local) * NB + (size_t)(tb + bl);
        ((float4*)Alp)[dst] = lp_t[bl][k_local];
        ((float4*)Blq)[dst] = lq_t[bl][k_local];
    }
}

// ---------------- Kernel 2: scan — loads and stores on DISJOINT buffers ----------
// Loads: A (lp_p), B (lq_p), both const restrict. Stores: g_P only. No aliasing ->
// the compiler keeps the double-buffered prefetch with counted vmcnt (no vmcnt(0)
// drains, which cost R3 ~29cy/step). sched_barrier(0) fences pin the regions so the
// scheduler cannot sink the prefetch into the consume region.
// Per-row fp op sequence identical to verified R5 scan_step_p -> bit-exact.
__device__ __forceinline__ void scan_step_p(float lp, float lq, float& S0, float& S1,
                                            float& po) {
    const float L2E = 1.44269504088896340736f;   // log2(e)
    const float LN2 = 0.69314718055994530942f;   // ln(2)
    float x1 = S0 + lp;
    float x2 = S1 + lq;
    float d  = x1 - x2;                          // never NaN (x1 finite)
    float m  = fmaxf(x1, x2);
    float z  = fabsf(d) * -L2E;
    float e  = __builtin_amdgcn_exp2f(z);        // exp2(-inf)=0 handles S1=-inf start
    float a  = 1.0f + e;
    float l  = __builtin_amdgcn_logf(a);
    S1 = fmaf(l, LN2, m);
    S0 = S0 + lq;
    po = fminf(x1 - S1, 0.0f);                   // decide's p, same op order as R3/R5
}

#define CH 8  // float4-groups per chunk (32 items)
#define SB() __builtin_amdgcn_sched_barrier(0)

__global__ __launch_bounds__(64, 1) void scan_kernel(const float* __restrict__ A,
                                                     const float* __restrict__ B) {
    int row = blockIdx.x * 64 + threadIdx.x;  // 8 blocks x 64 lanes = 512 rows
    const float4* Ap = (const float4*)A;      // float4 index: g*NB + row
    const float4* Bp = (const float4*)B;
    float4* Pp = (float4*)g_P;

    float S0 = 0.0f, S1 = -INFINITY;
    float4 lpE[CH], lqE[CH], lpO[CH], lqO[CH];

    // prologue: chunk 0 -> E, chunk 1 -> O (compiler inserts counted waits before use)
#pragma unroll
    for (int j = 0; j < CH; ++j) {
        lpE[j] = Ap[(size_t)j * NB + row];
        lqE[j] = Bp[(size_t)j * NB + row];
    }
#pragma unroll
    for (int j = 0; j < CH; ++j) {
        lpO[j] = Ap[(size_t)(CH + j) * NB + row];
        lqO[j] = Bp[(size_t)(CH + j) * NB + row];
    }

    const int NCHUNK = NG / CH;  // 256 (pow2)
    for (int c = 0; c < NCHUNK; c += 2) {
        SB();
        // consume chunk c from E, store p to g_P
#pragma unroll
        for (int j = 0; j < CH; ++j) {
            float4 p4;
            scan_step_p(lpE[j].x, lqE[j].x, S0, S1, p4.x);
            scan_step_p(lpE[j].y, lqE[j].y, S0, S1, p4.y);
            scan_step_p(lpE[j].z, lqE[j].z, S0, S1, p4.z);
            scan_step_p(lpE[j].w, lqE[j].w, S0, S1, p4.w);
            Pp[(size_t)(c * CH + j) * NB + row] = p4;
        }
        SB();
        // prefetch chunk c+2 -> E (wrap keeps last-iter loads in-bounds; values unused)
        {
            int g2 = ((c + 2) & (NCHUNK - 1)) * CH;
#pragma unroll
            for (int j = 0; j < CH; ++j) {
                lpE[j] = Ap[(size_t)(g2 + j) * NB + row];
                lqE[j] = Bp[(size_t)(g2 + j) * NB + row];
            }
        }
        SB();
        // consume chunk c+1 from O
#pragma unroll
        for (int j = 0; j < CH; ++j) {
            float4 p4;
            scan_step_p(lpO[j].x, lqO[j].x, S0, S1, p4.x);
            scan_step_p(lpO[j].y, lqO[j].y, S0, S1, p4.y);
            scan_step_p(lpO[j].z, lqO[j].z, S0, S1, p4.z);
            scan_step_p(lpO[j].w, lqO[j].w, S0, S1, p4.w);
            Pp[(size_t)((c + 1) * CH + j) * NB + row] = p4;
        }
        SB();
        // prefetch chunk c+3 -> O
        {
            int g3 = ((c + 3) & (NCHUNK - 1)) * CH;
#pragma unroll
            for (int j = 0; j < CH; ++j) {
                lpO[j] = Ap[(size_t)(g3 + j) * NB + row];
                lqO[j] = Bp[(size_t)(g3 + j) * NB + row];
            }
        }
    }
}

// ---------------- Kernel 3: decide + one-hot write (fused; reads g_P, writes out) ------
// Predicate math/op-order identical to verified R0/R3/R5 decide; one-hot tail is the
// verified R0 structure. g_P never aliases out -> fusion is race-free.
__global__ __launch_bounds__(256) void decide_kernel(const float* __restrict__ noise,
                                                     float* __restrict__ out) {
    int row = blockIdx.x;
    const float4* pp = (const float4*)g_P;
    const float4* ur = (const float4*)(noise + (size_t)row * NI);
    float4* outr = (float4*)(out + (size_t)row * NI);
    int tid = threadIdx.x;

    int best = -1;
#pragma unroll
    for (int k = 0; k < NG / 256; ++k) {  // 8
        int g = tid + k * 256;
        float4 p4 = pp[(size_t)g * NB + row];
        float4 u = ur[g];
#pragma unroll
        for (int j = 0; j < 4; ++j) {
            float p = (&p4.x)[j];
            float q = log1mexp_f(p);            // p==0 -> -inf -> prob 1
            float z = p - q;
            float prob = 1.0f / (1.0f + expf(-z));
            if ((&u.x)[j] < prob) {
                int i = 4 * g + j;
                best = (i > best) ? i : best;
            }
        }
    }

#pragma unroll
    for (int off = 32; off > 0; off >>= 1) {
        int o = __shfl_down(best, off);
        best = (o > best) ? o : best;
    }
    __shared__ int lds[4];
    __shared__ int sel_s;
    int wid = tid >> 6;
    if ((tid & 63) == 0) lds[wid] = best;
    __syncthreads();
    if (tid == 0) {
        int s01 = (lds[0] > lds[1]) ? lds[0] : lds[1];
        int s23 = (lds[2] > lds[3]) ? lds[2] : lds[3];
        sel_s = (s01 > s23) ? s01 : s23;
    }
    __syncthreads();
    int sel = sel_s;

#pragma unroll
    for (int k = 0; k < NG / 256; ++k) {
        int g = tid + k * 256;
        int i0 = 4 * g;
        float4 v;
        v.x = (i0 == sel) ? 1.0f : 0.0f;
        v.y = (i0 + 1 == sel) ? 1.0f : 0.0f;
        v.z = (i0 + 2 == sel) ? 1.0f : 0.0f;
        v.w = (i0 + 3 == sel) ? 1.0f : 0.0f;
        outr[g] = v;
    }
}

extern "C" void kernel_launch(void* const* d_in, const int* in_sizes, int n_in,
                              void* d_out, int out_size, void* d_ws, size_t ws_size,
                              hipStream_t stream) {
    (void)in_sizes; (void)n_in; (void)out_size; (void)ws_size;
    const float* logits = (const float*)d_in[0];
    const float* noise = (const float*)d_in[1];
    float* out = (float*)d_out;       // lq_p -> final 0/1 output (16 MB)
    float* A = (float*)d_ws;          // lp_p (16 MB of ws)

    prep_kernel<<<8 * (NG / TK), 256, 0, stream>>>(logits, A, out);  // 1024 blocks
    scan_kernel<<<8, 64, 0, stream>>>(A, out);
    decide_kernel<<<NB, 256, 0, stream>>>(noise, out);
}

// Round 10
// 418.311 us; speedup vs baseline: 1.7564x; 1.0054x over previous
//
#include <hip/hip_runtime.h>
#include <math.h>
#include <stdint.h>

#define NB 512
#define NI 8192
#define NG (NI / 4)   // 2048 float4 item-groups per row
#define NLOG2 0.69314718055994530942f

__device__ __forceinline__ float log1mexp_f(float x) {
    // log(1 - exp(x)) for x <= 0, matching reference branch structure (precise ocml)
    return (x > -NLOG2) ? logf(-expm1f(x)) : log1pf(-expf(x));
}

// Scan output p: module-allocated, disjoint from scan's load streams and from out.
__device__ float g_P[(size_t)NB * NI];

// ---------------- Kernel 1: prep + pack-transpose (verified R3/R5/R8, unchanged) -------
// float4 index (g*NB + b) holds items 4g..4g+3 of row b -> scan accesses fully coalesced.
#define TB 64   // rows per tile
#define TK 16   // float4-groups per tile (64 items)
__global__ __launch_bounds__(256) void prep_kernel(const float* __restrict__ logits,
                                                   float* __restrict__ Alp,   // ws: lp_p
                                                   float* __restrict__ Blq) { // out: lq_p
    __shared__ float4 lp_t[TB][TK + 1];
    __shared__ float4 lq_t[TB][TK + 1];
    int bx = blockIdx.x;
    int tb = (bx & 7) * TB;        // row-tile base (512/64 = 8 tiles)
    int tkb = (bx >> 3) * TK;      // group-tile base (2048/16 = 128 tiles)
    int t = threadIdx.x;

    int kl = t & 15;
    int rl0 = t >> 4;  // 0..15
#pragma unroll
    for (int r = 0; r < 4; ++r) {
        int row_local = r * 16 + rl0;
        float4 x4 = *(const float4*)&logits[(size_t)(tb + row_local) * NI + (size_t)(tkb + kl) * 4];
        float4 lp4, lq4;
        const float* xs = &x4.x;
        float* lps = &lp4.x;
        float* lqs = &lq4.x;
#pragma unroll
        for (int j = 0; j < 4; ++j) {
            float x = xs[j];
            float lp = -(fmaxf(-x, 0.0f) + log1pf(expf(-fabsf(x))));
            lp = fminf(lp, -1e-7f);
            lps[j] = lp;
            lqs[j] = log1mexp_f(lp);
        }
        lp_t[row_local][kl] = lp4;
        lq_t[row_local][kl] = lq4;
    }
    __syncthreads();

    int bl = t & 63;
    int kw0 = t >> 6;  // 0..3
#pragma unroll
    for (int w = 0; w < 4; ++w) {
        int k_local = w * 4 + kw0;
        size_t dst = (size_t)(tkb + k_local) * NB + (size_t)(tb + bl);
        ((float4*)Alp)[dst] = lp_t[bl][k_local];
        ((float4*)Blq)[dst] = lq_t[bl][k_local];
    }
}

// ---------------- Kernel 2: WAVE-RELAY scan ----------
// 8 blocks x 4 waves. All 4 waves serve the same 64 rows; wave w computes chunks
// c === w (mod 4), state (S0,S1) hands off through LDS at a __syncthreads per chunk.
// Each wave issues its next chunk's loads at the END of its turn -> ~3 chunk-times
// (~3800 cy) of enforced prefetch distance, immune to compiler scheduling heuristics
// (the failure mode of R3/R6/R7/R8). Per-row fp op sequence identical to verified
// R5/R8 scan_step_p -> bit-exact.
__device__ __forceinline__ void scan_step_p(float lp, float lq, float& S0, float& S1,
                                            float& po) {
    const float L2E = 1.44269504088896340736f;   // log2(e)
    const float LN2 = 0.69314718055994530942f;   // ln(2)
    float x1 = S0 + lp;
    float x2 = S1 + lq;
    float d  = x1 - x2;                          // never NaN (x1 finite)
    float m  = fmaxf(x1, x2);
    float z  = fabsf(d) * -L2E;
    float e  = __builtin_amdgcn_exp2f(z);        // exp2(-inf)=0 handles S1=-inf start
    float a  = 1.0f + e;
    float l  = __builtin_amdgcn_logf(a);
    S1 = fmaf(l, LN2, m);
    S0 = S0 + lq;
    po = fminf(x1 - S1, 0.0f);                   // decide's p, same op order as R3/R5/R8
}

#define CHR 8   // float4-groups per relay turn (32 items)
#define WV 4    // waves per block

__global__ __launch_bounds__(256, 1) void scan_kernel(const float* __restrict__ A,
                                                      const float* __restrict__ B) {
    int lane = threadIdx.x & 63;
    int w = threadIdx.x >> 6;                 // wave id 0..3
    int row = blockIdx.x * 64 + lane;         // 8 blocks x 64 rows
    const float4* Ap = (const float4*)A;      // float4 index: g*NB + row
    const float4* Bp = (const float4*)B;
    float4* Pp = (float4*)g_P;

    __shared__ float S0s[64], S1s[64];
    if (threadIdx.x < 64) { S0s[threadIdx.x] = 0.0f; S1s[threadIdx.x] = -INFINITY; }

    // prologue: each wave issues loads for its first chunk (c = w)
    float4 lpR[CHR], lqR[CHR];
#pragma unroll
    for (int j = 0; j < CHR; ++j) {
        lpR[j] = Ap[(size_t)(w * CHR + j) * NB + row];
        lqR[j] = Bp[(size_t)(w * CHR + j) * NB + row];
    }
    __syncthreads();  // state init visible

    const int NCHUNK = NG / CHR;  // 256
    for (int c = 0; c < NCHUNK; ++c) {
        if ((c & (WV - 1)) == w) {            // wave-uniform branch
            float S0 = S0s[lane];
            float S1 = S1s[lane];
#pragma unroll
            for (int j = 0; j < CHR; ++j) {
                float4 p4;
                scan_step_p(lpR[j].x, lqR[j].x, S0, S1, p4.x);
                scan_step_p(lpR[j].y, lqR[j].y, S0, S1, p4.y);
                scan_step_p(lpR[j].z, lqR[j].z, S0, S1, p4.z);
                scan_step_p(lpR[j].w, lqR[j].w, S0, S1, p4.w);
                Pp[(size_t)(c * CHR + j) * NB + row] = p4;
            }
            S0s[lane] = S0;
            S1s[lane] = S1;
            int cn = c + WV;                  // issue loads for my next turn
            if (cn < NCHUNK) {
#pragma unroll
                for (int j = 0; j < CHR; ++j) {
                    lpR[j] = Ap[(size_t)(cn * CHR + j) * NB + row];
                    lqR[j] = Bp[(size_t)(cn * CHR + j) * NB + row];
                }
            }
        }
        __syncthreads();                      // hand state to the next wave
    }
}

// ---------------- Kernel 3: decide + one-hot write (verified R8, unchanged) ------------
__global__ __launch_bounds__(256) void decide_kernel(const float* __restrict__ noise,
                                                     float* __restrict__ out) {
    int row = blockIdx.x;
    const float4* pp = (const float4*)g_P;
    const float4* ur = (const float4*)(noise + (size_t)row * NI);
    float4* outr = (float4*)(out + (size_t)row * NI);
    int tid = threadIdx.x;

    int best = -1;
#pragma unroll
    for (int k = 0; k < NG / 256; ++k) {  // 8
        int g = tid + k * 256;
        float4 p4 = pp[(size_t)g * NB + row];
        float4 u = ur[g];
#pragma unroll
        for (int j = 0; j < 4; ++j) {
            float p = (&p4.x)[j];
            float q = log1mexp_f(p);            // p==0 -> -inf -> prob 1
            float z = p - q;
            float prob = 1.0f / (1.0f + expf(-z));
            if ((&u.x)[j] < prob) {
                int i = 4 * g + j;
                best = (i > best) ? i : best;
            }
        }
    }

#pragma unroll
    for (int off = 32; off > 0; off >>= 1) {
        int o = __shfl_down(best, off);
        best = (o > best) ? o : best;
    }
    __shared__ int lds[4];
    __shared__ int sel_s;
    int wid = tid >> 6;
    if ((tid & 63) == 0) lds[wid] = best;
    __syncthreads();
    if (tid == 0) {
        int s01 = (lds[0] > lds[1]) ? lds[0] : lds[1];
        int s23 = (lds[2] > lds[3]) ? lds[2] : lds[3];
        sel_s = (s01 > s23) ? s01 : s23;
    }
    __syncthreads();
    int sel = sel_s;

#pragma unroll
    for (int k = 0; k < NG / 256; ++k) {
        int g = tid + k * 256;
        int i0 = 4 * g;
        float4 v;
        v.x = (i0 == sel) ? 1.0f : 0.0f;
        v.y = (i0 + 1 == sel) ? 1.0f : 0.0f;
        v.z = (i0 + 2 == sel) ? 1.0f : 0.0f;
        v.w = (i0 + 3 == sel) ? 1.0f : 0.0f;
        outr[g] = v;
    }
}

extern "C" void kernel_launch(void* const* d_in, const int* in_sizes, int n_in,
                              void* d_out, int out_size, void* d_ws, size_t ws_size,
                              hipStream_t stream) {
    (void)in_sizes; (void)n_in; (void)out_size; (void)ws_size;
    const float* logits = (const float*)d_in[0];
    const float* noise = (const float*)d_in[1];
    float* out = (float*)d_out;       // lq_p -> final 0/1 output (16 MB)
    float* A = (float*)d_ws;          // lp_p (16 MB of ws)

    prep_kernel<<<8 * (NG / TK), 256, 0, stream>>>(logits, A, out);  // 1024 blocks
    scan_kernel<<<8, 256, 0, stream>>>(A, out);
    decide_kernel<<<NB, 256, 0, stream>>>(noise, out);
}